// Round 5
// baseline (745.249 us; speedup 1.0000x reference)
//
#include <hip/hip_runtime.h>
#include <hip/hip_bf16.h>

// GraphLSTM: B=128, S=128, N=24, F=16, H=32 -> IS=384, HS=768, gates=3072.
// R12 on top of R11 (591us, flag barrier):
//  * x B-frags loaded directly from global (L2-hot, immutable) -> x LDS
//    region, x staging, and 12/36 ds_reads per wave removed.
//  * MFMA split: x-part (kk<12) for step t+1 computed BETWEEN flag publish
//    and flag poll -> 24 MFMAs + 12 loads now fill the idle flag RTT.
//  * h LDS layout: row pitch 1584 B ( /4 mod 32 == 12 -> read window
//    (3m+quad) mod 8, even 8-lane spread = BW floor), linear addressing,
//    ds_read_b128 offsets fold to immediates. Old layout had skewed
//    (m + quad^(m&3)) windows -> the stable 4.25e7 conflict cycles.
//  * bulk h load as 12 u64 agent loads/thread (R10-proven) + ds_write_b64.
//  * all 4 waves poll flags themselves -> 2 syncthreads/step (was 3).
// Accumulation order identical to R11 (kk ascending) -> same absmax.

typedef __bf16 bf16x8 __attribute__((ext_vector_type(8)));
typedef float f32x4 __attribute__((ext_vector_type(4)));

#define HS 768
#define GATES 3072
#define KV 1152          // combined K: 384 (W) + 768 (U)
#define SEQ 128
#define BATCH 128
#define OUT_HID (BATCH*SEQ*HS)
#define LPITCH 1584      // h LDS row pitch (bytes); /4 % 32 == 12
#define NWG 192
#define TEAM_WGS 24

__device__ __forceinline__ float fast_sig(float x) {
    return 1.0f / (1.0f + __expf(-x));
}
__device__ __forceinline__ float fast_tanh(float x) {
    x = fminf(fmaxf(x, -15.0f), 15.0f);
    float e = __expf(2.0f * x);
    return (e - 1.0f) / (e + 1.0f);
}

// convert 8 consecutive fp32 -> bf16x8 (RNE via cast)
__device__ __forceinline__ bf16x8 cvt8(const float* src) {
    float4 v0 = *(const float4*)src;
    float4 v1 = *(const float4*)(src + 4);
    bf16x8 p;
    p[0] = (__bf16)v0.x; p[1] = (__bf16)v0.y; p[2] = (__bf16)v0.z; p[3] = (__bf16)v0.w;
    p[4] = (__bf16)v1.x; p[5] = (__bf16)v1.y; p[6] = (__bf16)v1.z; p[7] = (__bf16)v1.w;
    return p;
}

// ---------------------------------------------------------------------------
// Kernel 1: masked + transposed weights (fp32 in, bf16 out).   [R4-validated]
// ---------------------------------------------------------------------------
__global__ void prep_kernel(const float* __restrict__ W, const float* __restrict__ U,
                            const float* __restrict__ G, __bf16* __restrict__ VmT) {
    __shared__ __bf16 tile[64][65];
    const int kvb = blockIdx.x * 64;
    const int cb  = blockIdx.y * 64;
    const int tid = threadIdx.x;
    {
        const int cl = tid & 63, kl0 = tid >> 6;
        #pragma unroll
        for (int i = 0; i < 16; ++i) {
            int kl = kl0 + i * 4;
            int kv = kvb + kl;
            int c  = cb + cl;
            int nout = (c % HS) >> 5;
            float g, v;
            if (kv < 384) {
                g = G[(kv >> 4) * 24 + nout];
                v = W[(size_t)kv * GATES + c];
            } else {
                int ku = kv - 384;
                g = G[(ku >> 5) * 24 + nout];
                v = U[(size_t)ku * GATES + c];
            }
            tile[kl][cl] = (__bf16)(v * g);
        }
    }
    __syncthreads();
    {
        const int kl = tid & 63, cl0 = tid >> 6;
        #pragma unroll
        for (int i = 0; i < 16; ++i) {
            int c = cl0 + i * 4;
            VmT[(size_t)(cb + c) * KV + kvb + kl] = tile[kl][c];
        }
    }
}

// ---------------------------------------------------------------------------
// Kernel 2: x fp32 [b][t][384] -> bf16 [t][b][384]
// ---------------------------------------------------------------------------
__global__ void prep_x(const float* __restrict__ x, __bf16* __restrict__ xb) {
    const int g = blockIdx.x * 256 + threadIdx.x;
    const int e = g * 8;
    const int b = e / (SEQ * 384);
    const int rem = e - b * (SEQ * 384);
    const int t = rem / 384;
    const int k = rem - t * 384;
    *(bf16x8*)&xb[((size_t)t * BATCH + b) * 384 + k] = cvt8(&x[e]);
}

// ---------------------------------------------------------------------------
// Kernel 3: persistent scan. 8 teams x 24 WGs = 192 WGs, 1 WG/CU.
// bar layout (16 KB, zeroed per launch):
//   flags: u32[8][24][16] -- one 64B line per (team,wg), value = t+1
// Per step: h-part MFMA (24 ds_read_b128, LDS) -> LSTM -> exchange store +
// out stores -> sync (a, drains vmcnt) -> tid0 flag -> x-part MFMA for t+1
// (global loads, overlaps flag RTT) -> all-wave flag poll -> 12 u64 bulk h
// loads -> 12 ds_write_b64 -> sync (b).
// ---------------------------------------------------------------------------
__global__ __launch_bounds__(256, 1) void scan_kernel(
        const __bf16* __restrict__ xb,     // [t][b][384] bf16
        const float* __restrict__ h0,
        const float* __restrict__ c0,
        const __bf16* __restrict__ VmT,    // [3072][1152] bf16
        const float* __restrict__ bias,
        float* out,
        unsigned* xh32,                    // [2][128][384] packed bf16 pairs
        unsigned* bar) {
    __shared__ __align__(16) char Bs[16 * LPITCH];   // 25344 B, h only
    const int tid = threadIdx.x;
    const int lane = tid & 63, wv = tid >> 6;
    const int m = lane & 15, quad = lane >> 4;
    const int team = blockIdx.x & 7, wg = blockIdx.x >> 3;
    const int bbase = team * 16;
    const int jbase = wg * 32 + wv * 8;

    unsigned* flags = bar;                              // [8][24][16]
    unsigned* myflag = flags + (team * TEAM_WGS + wg) * 16;

    // --- weights -> registers (read VmT exactly once for the whole scan) ---
    bf16x8 w[2][36];
    #pragma unroll
    for (int T = 0; T < 2; ++T) {
        const int cg = (m & 3) * HS + jbase + 2 * (m >> 2) + T;
        const __bf16* wp = VmT + (size_t)cg * KV;
        #pragma unroll
        for (int kk = 0; kk < 36; ++kk)
            w[T][kk] = *(const bf16x8*)(wp + kk * 32 + quad * 8);
    }

    const int b_own = bbase + m;
    const int j0 = jbase + 2 * quad;       // even
    const int j1 = j0 + 1;                 // odd (adjacent -> one u32)
    float cv0 = c0[b_own * HS + j0];
    float cv1 = c0[b_own * HS + j1];
    f32x4 bias0, bias1;
    #pragma unroll
    for (int r = 0; r < 4; ++r) {
        bias0[r] = bias[r * HS + j0];
        bias1[r] = bias[r * HS + j1];
    }

    // --- pre-stage h0 into LDS (bf16, linear-window layout) ---
    #pragma unroll
    for (int i = 0; i < 6; ++i) {
        int ch = tid + i * 256;            // 1536 chunks (bf16x8)
        int row = ch / 96, c8h = ch % 96;
        bf16x8 p = cvt8(&h0[(size_t)(bbase + row) * HS + c8h * 8]);
        *(bf16x8*)(Bs + row * LPITCH + c8h * 16) = p;
    }
    __syncthreads();

    // --- phase A accumulators for step 0: bias + x-part (kk 0..11) ---
    f32x4 accA0 = bias0, accA1 = bias1;
    {
        const __bf16* xrow = xb + ((size_t)0 * BATCH + bbase + m) * 384 + quad * 8;
        #pragma unroll
        for (int kk = 0; kk < 12; ++kk) {
            bf16x8 xf = *(const bf16x8*)(xrow + kk * 32);
            accA0 = __builtin_amdgcn_mfma_f32_16x16x32_bf16(w[0][kk], xf, accA0, 0, 0, 0);
            accA1 = __builtin_amdgcn_mfma_f32_16x16x32_bf16(w[1][kk], xf, accA1, 0, 0, 0);
        }
    }

    #pragma unroll 1
    for (int t = 0; t < SEQ; ++t) {
        // phase B: h-part (kk 12..35) from LDS
        f32x4 acc0 = accA0, acc1 = accA1;
        const char* hbase = Bs + m * LPITCH + quad * 16;
        #pragma unroll
        for (int p = 0; p < 24; ++p) {
            bf16x8 bf = *(const bf16x8*)(hbase + p * 64);
            acc0 = __builtin_amdgcn_mfma_f32_16x16x32_bf16(w[0][12 + p], bf, acc0, 0, 0, 0);
            acc1 = __builtin_amdgcn_mfma_f32_16x16x32_bf16(w[1][12 + p], bf, acc1, 0, 0, 0);
        }

        // LSTM elementwise (lane-local: acc reg index == gate i,f,g,o)
        float h0v, h1v;
        {
            float ii = fast_sig(acc0[0]), ff = fast_sig(acc0[1]);
            float gg = fast_tanh(acc0[2]), oo = fast_sig(acc0[3]);
            cv0 = ff * cv0 + ii * gg;
            h0v = oo * fast_tanh(cv0);
        }
        {
            float ii = fast_sig(acc1[0]), ff = fast_sig(acc1[1]);
            float gg = fast_tanh(acc1[2]), oo = fast_sig(acc1[3]);
            cv1 = ff * cv1 + ii * gg;
            h1v = oo * fast_tanh(cv1);
        }

        if (t == SEQ - 1) {
            const size_t obase = ((size_t)b_own * SEQ + t) * HS;
            *(float2*)&out[obase + j0] = make_float2(h0v, h1v);
            *(float2*)&out[OUT_HID + b_own * HS + j0] = make_float2(h0v, h1v);
            *(float2*)&out[OUT_HID + BATCH * HS + b_own * HS + j0] = make_float2(cv0, cv1);
            break;
        }

        // exchange store FIRST (earliest global visibility; relaxed, no RMW)
        {
            unsigned lo = (unsigned)__builtin_bit_cast(unsigned short, (__bf16)h0v);
            unsigned hi = (unsigned)__builtin_bit_cast(unsigned short, (__bf16)h1v);
            unsigned* dst = xh32 + ((size_t)(t & 1) * BATCH + b_own) * 384
                                 + (jbase >> 1) + quad;
            __hip_atomic_store(dst, lo | (hi << 16), __ATOMIC_RELAXED,
                               __HIP_MEMORY_SCOPE_AGENT);
        }
        {
            const size_t obase = ((size_t)b_own * SEQ + t) * HS;
            *(float2*)&out[obase + j0] = make_float2(h0v, h1v);
        }

        __syncthreads();   // (a) LDS reads done + all waves' stores vmcnt-drained

        // publish: one relaxed flag store per WG (own 64B line, no RMW)
        if (tid == 0)
            __hip_atomic_store(myflag, (unsigned)(t + 1), __ATOMIC_RELAXED,
                               __HIP_MEMORY_SCOPE_AGENT);

        // phase A for step t+1: bias + x-part (overlaps flag propagation)
        accA0 = bias0; accA1 = bias1;
        {
            const __bf16* xrow = xb + ((size_t)(t + 1) * BATCH + bbase + m) * 384
                               + quad * 8;
            #pragma unroll
            for (int kk = 0; kk < 12; ++kk) {
                bf16x8 xf = *(const bf16x8*)(xrow + kk * 32);
                accA0 = __builtin_amdgcn_mfma_f32_16x16x32_bf16(w[0][kk], xf, accA0, 0, 0, 0);
                accA1 = __builtin_amdgcn_mfma_f32_16x16x32_bf16(w[1][kk], xf, accA1, 0, 0, 0);
            }
        }

        // team barrier: every wave polls the 24 flag lines itself (lanes<24)
        if (lane < TEAM_WGS) {
            const unsigned* fp = flags + (team * TEAM_WGS + lane) * 16;
            while (__hip_atomic_load(fp, __ATOMIC_RELAXED,
                                     __HIP_MEMORY_SCOPE_AGENT) < (unsigned)(t + 1)) {
            }
        }
        // no barrier needed: each wave verified all flags itself; LDS writes
        // below only become visible to other waves after sync (b).

        // bulk h load: 16 rows x 192 u64 = 3072 (12 per thread), ONCE
        {
            const unsigned long long* src64 =
                (const unsigned long long*)xh32 + (size_t)(t & 1) * BATCH * 192;
            unsigned long long v[12];
            #pragma unroll
            for (int i = 0; i < 12; ++i) {
                int g = tid + i * 256;             // 0..3071
                int row = g / 192, du = g % 192;
                v[i] = __hip_atomic_load(&src64[(size_t)(bbase + row) * 192 + du],
                                         __ATOMIC_RELAXED, __HIP_MEMORY_SCOPE_AGENT);
            }
            #pragma unroll
            for (int i = 0; i < 12; ++i) {
                int g = tid + i * 256;
                int row = g / 192, du = g % 192;
                *(unsigned long long*)(Bs + row * LPITCH + du * 8) = v[i];
            }
        }
        __syncthreads();   // (b) new h visible to all waves
    }
}

// ---------------------------------------------------------------------------
extern "C" void kernel_launch(void* const* d_in, const int* in_sizes, int n_in,
                              void* d_out, int out_size, void* d_ws, size_t ws_size,
                              hipStream_t stream) {
    (void)in_sizes; (void)n_in; (void)out_size; (void)ws_size;
    const float* x    = (const float*)d_in[0];
    const float* h0   = (const float*)d_in[1];
    const float* c0   = (const float*)d_in[2];
    const float* W    = (const float*)d_in[3];
    const float* U    = (const float*)d_in[4];
    const float* bias = (const float*)d_in[5];
    const float* G    = (const float*)d_in[6];
    float* out = (float*)d_out;

    char* wsb = (char*)d_ws;
    unsigned* bar = (unsigned*)wsb;                                    // 16 KB
    __bf16* VmT  = (__bf16*)(wsb + 16384);                             // 6.75 MB
    __bf16* xb   = (__bf16*)(wsb + 16384 + (size_t)GATES * KV * 2);    // 12.6 MB
    unsigned* xh32 = (unsigned*)(wsb + 16384 + (size_t)GATES * KV * 2
                                      + (size_t)SEQ * BATCH * 384 * 2);   // 393 KB

    hipMemsetAsync(bar, 0, 16384, stream);
    prep_kernel<<<dim3(18, 48), 256, 0, stream>>>(W, U, G, VmT);
    prep_x<<<dim3(3072), 256, 0, stream>>>(x, xb);
    scan_kernel<<<dim3(NWG), dim3(256), 0, stream>>>(xb, h0, c0, VmT, bias,
                                                     out, xh32, bar);
}

// Round 6
// 580.279 us; speedup vs baseline: 1.2843x; 1.2843x over previous
//
#include <hip/hip_runtime.h>
#include <hip/hip_bf16.h>

// GraphLSTM: B=128, S=128, N=24, F=16, H=32 -> IS=384, HS=768, gates=3072.
// R13 = R11 (591us total, proven structure: flag-line barrier, wave0 poll,
// 3 syncs/step, x staged in LDS) + ONLY the R12-validated conflict-free LDS
// layout. Unified row [x: 768B][h: 1536B], pitch 2352B (2352/16=147, 147%8
// ==3 -> a wave's 64 ds_read_b128 lanes spread 8-per-16B-slot window ->
// conflict-free; R12 measured 4.25e7 -> 9.4e6 with this window math).
// Linear addressing (no XOR swizzle), kk=0..35 spans x then h contiguously
// -> identical accumulation order to R11 -> same absmax. R12's regressions
// (4-wave poll contention, per-step global x loads) are reverted.

typedef __bf16 bf16x8 __attribute__((ext_vector_type(8)));
typedef float f32x4 __attribute__((ext_vector_type(4)));

#define HS 768
#define GATES 3072
#define KV 1152          // combined K: 384 (W) + 768 (U)
#define SEQ 128
#define BATCH 128
#define OUT_HID (BATCH*SEQ*HS)
#define LROW 2352        // LDS row pitch (bytes); /16 % 8 == 3 -> even spread
#define XOFF 768         // h region starts at byte 768 within a row
#define NWG 192
#define TEAM_WGS 24

__device__ __forceinline__ float fast_sig(float x) {
    return 1.0f / (1.0f + __expf(-x));
}
__device__ __forceinline__ float fast_tanh(float x) {
    x = fminf(fmaxf(x, -15.0f), 15.0f);
    float e = __expf(2.0f * x);
    return (e - 1.0f) / (e + 1.0f);
}

// convert 8 consecutive fp32 -> bf16x8 (RNE via cast)
__device__ __forceinline__ bf16x8 cvt8(const float* src) {
    float4 v0 = *(const float4*)src;
    float4 v1 = *(const float4*)(src + 4);
    bf16x8 p;
    p[0] = (__bf16)v0.x; p[1] = (__bf16)v0.y; p[2] = (__bf16)v0.z; p[3] = (__bf16)v0.w;
    p[4] = (__bf16)v1.x; p[5] = (__bf16)v1.y; p[6] = (__bf16)v1.z; p[7] = (__bf16)v1.w;
    return p;
}

// ---------------------------------------------------------------------------
// Kernel 1: masked + transposed weights (fp32 in, bf16 out).   [R4-validated]
// ---------------------------------------------------------------------------
__global__ void prep_kernel(const float* __restrict__ W, const float* __restrict__ U,
                            const float* __restrict__ G, __bf16* __restrict__ VmT) {
    __shared__ __bf16 tile[64][65];
    const int kvb = blockIdx.x * 64;
    const int cb  = blockIdx.y * 64;
    const int tid = threadIdx.x;
    {
        const int cl = tid & 63, kl0 = tid >> 6;
        #pragma unroll
        for (int i = 0; i < 16; ++i) {
            int kl = kl0 + i * 4;
            int kv = kvb + kl;
            int c  = cb + cl;
            int nout = (c % HS) >> 5;
            float g, v;
            if (kv < 384) {
                g = G[(kv >> 4) * 24 + nout];
                v = W[(size_t)kv * GATES + c];
            } else {
                int ku = kv - 384;
                g = G[(ku >> 5) * 24 + nout];
                v = U[(size_t)ku * GATES + c];
            }
            tile[kl][cl] = (__bf16)(v * g);
        }
    }
    __syncthreads();
    {
        const int kl = tid & 63, cl0 = tid >> 6;
        #pragma unroll
        for (int i = 0; i < 16; ++i) {
            int c = cl0 + i * 4;
            VmT[(size_t)(cb + c) * KV + kvb + kl] = tile[kl][c];
        }
    }
}

// ---------------------------------------------------------------------------
// Kernel 2: x fp32 [b][t][384] -> bf16 [t][b][384]
// ---------------------------------------------------------------------------
__global__ void prep_x(const float* __restrict__ x, __bf16* __restrict__ xb) {
    const int g = blockIdx.x * 256 + threadIdx.x;
    const int e = g * 8;
    const int b = e / (SEQ * 384);
    const int rem = e - b * (SEQ * 384);
    const int t = rem / 384;
    const int k = rem - t * 384;
    *(bf16x8*)&xb[((size_t)t * BATCH + b) * 384 + k] = cvt8(&x[e]);
}

// ---------------------------------------------------------------------------
// Kernel 3: persistent scan. 8 teams x 24 WGs = 192 WGs, 1 WG/CU.
// bar layout (16 KB, zeroed per launch):
//   flags: u32[8][24][16] -- one 64B line per (team,wg), value = t+1
// Per step: MFMA(72, 36 ds_read_b128 conflict-free) -> LSTM -> exchange
// store (relaxed) + out stores -> sync (a, drains vmcnt) -> tid0 flag ->
// stage x_{t+1} (overlaps flag RTT) -> wave0 polls 24 flag lines -> sync ->
// bulk h load (12 u64/thread) -> LDS write -> sync (b).
// ---------------------------------------------------------------------------
__global__ __launch_bounds__(256, 1) void scan_kernel(
        const __bf16* __restrict__ xb,     // [t][b][384] bf16
        const float* __restrict__ h0,
        const float* __restrict__ c0,
        const __bf16* __restrict__ VmT,    // [3072][1152] bf16
        const float* __restrict__ bias,
        float* out,
        unsigned* xh32,                    // [2][128][384] packed bf16 pairs
        unsigned* bar) {
    __shared__ __align__(16) char Bs[16 * LROW];   // 37632 B
    const int tid = threadIdx.x;
    const int lane = tid & 63, wv = tid >> 6;
    const int m = lane & 15, quad = lane >> 4;
    const int team = blockIdx.x & 7, wg = blockIdx.x >> 3;
    const int bbase = team * 16;
    const int jbase = wg * 32 + wv * 8;

    unsigned* flags = bar;                              // [8][24][16]
    unsigned* myflag = flags + (team * TEAM_WGS + wg) * 16;

    // --- weights -> registers (read VmT exactly once for the whole scan) ---
    bf16x8 w[2][36];
    #pragma unroll
    for (int T = 0; T < 2; ++T) {
        const int cg = (m & 3) * HS + jbase + 2 * (m >> 2) + T;
        const __bf16* wp = VmT + (size_t)cg * KV;
        #pragma unroll
        for (int kk = 0; kk < 36; ++kk)
            w[T][kk] = *(const bf16x8*)(wp + kk * 32 + quad * 8);
    }

    const int b_own = bbase + m;
    const int j0 = jbase + 2 * quad;       // even
    const int j1 = j0 + 1;                 // odd (adjacent -> one u32)
    float cv0 = c0[b_own * HS + j0];
    float cv1 = c0[b_own * HS + j1];
    f32x4 bias0, bias1;
    #pragma unroll
    for (int r = 0; r < 4; ++r) {
        bias0[r] = bias[r * HS + j0];
        bias1[r] = bias[r * HS + j1];
    }

    // --- pre-loop staging: x_0 + h0 (both linear layout) ---
    #pragma unroll
    for (int i = 0; i < 3; ++i) {
        int ch = tid + i * 256;            // 768 x-chunks (16B)
        int row = ch / 48, c8 = ch % 48;
        *(uint4*)(Bs + row * LROW + c8 * 16) =
            *(const uint4*)&xb[((size_t)0 * BATCH + bbase + row) * 384 + c8 * 8];
    }
    #pragma unroll
    for (int i = 0; i < 6; ++i) {
        int ch = tid + i * 256;            // 1536 h-chunks (bf16x8)
        int row = ch / 96, c8h = ch % 96;
        bf16x8 p = cvt8(&h0[(size_t)(bbase + row) * HS + c8h * 8]);
        *(bf16x8*)(Bs + row * LROW + XOFF + c8h * 16) = p;
    }
    __syncthreads();

    #pragma unroll 1
    for (int t = 0; t < SEQ; ++t) {
        // gates = bias + [x_t ; h_{t-1}] @ [Wm ; Um]
        // kk*64 for kk=0..35 spans bytes [0,2304): x region then h region.
        f32x4 acc0 = bias0, acc1 = bias1;
        const char* bfrag = Bs + m * LROW + quad * 16;
        #pragma unroll
        for (int kk = 0; kk < 36; ++kk) {
            bf16x8 bf = *(const bf16x8*)(bfrag + kk * 64);
            acc0 = __builtin_amdgcn_mfma_f32_16x16x32_bf16(w[0][kk], bf, acc0, 0, 0, 0);
            acc1 = __builtin_amdgcn_mfma_f32_16x16x32_bf16(w[1][kk], bf, acc1, 0, 0, 0);
        }

        // LSTM elementwise (lane-local: acc reg index == gate i,f,g,o)
        float h0v, h1v;
        {
            float ii = fast_sig(acc0[0]), ff = fast_sig(acc0[1]);
            float gg = fast_tanh(acc0[2]), oo = fast_sig(acc0[3]);
            cv0 = ff * cv0 + ii * gg;
            h0v = oo * fast_tanh(cv0);
        }
        {
            float ii = fast_sig(acc1[0]), ff = fast_sig(acc1[1]);
            float gg = fast_tanh(acc1[2]), oo = fast_sig(acc1[3]);
            cv1 = ff * cv1 + ii * gg;
            h1v = oo * fast_tanh(cv1);
        }

        if (t == SEQ - 1) {
            const size_t obase = ((size_t)b_own * SEQ + t) * HS;
            *(float2*)&out[obase + j0] = make_float2(h0v, h1v);
            *(float2*)&out[OUT_HID + b_own * HS + j0] = make_float2(h0v, h1v);
            *(float2*)&out[OUT_HID + BATCH * HS + b_own * HS + j0] = make_float2(cv0, cv1);
            break;
        }

        // exchange store FIRST (earliest global visibility; relaxed, no RMW)
        {
            unsigned lo = (unsigned)__builtin_bit_cast(unsigned short, (__bf16)h0v);
            unsigned hi = (unsigned)__builtin_bit_cast(unsigned short, (__bf16)h1v);
            unsigned* dst = xh32 + ((size_t)(t & 1) * BATCH + b_own) * 384
                                 + (jbase >> 1) + quad;
            __hip_atomic_store(dst, lo | (hi << 16), __ATOMIC_RELAXED,
                               __HIP_MEMORY_SCOPE_AGENT);
        }
        {
            const size_t obase = ((size_t)b_own * SEQ + t) * HS;
            *(float2*)&out[obase + j0] = make_float2(h0v, h1v);
        }

        __syncthreads();   // (a) LDS reads done + all waves' stores vmcnt-drained

        // publish: one relaxed flag store per WG (own 64B line, no RMW)
        if (tid == 0)
            __hip_atomic_store(myflag, (unsigned)(t + 1), __ATOMIC_RELAXED,
                               __HIP_MEMORY_SCOPE_AGENT);

        // stage x_{t+1} (no cross-WG dependency; overlaps flag propagation)
        #pragma unroll
        for (int i = 0; i < 3; ++i) {
            int ch = tid + i * 256;
            int row = ch / 48, c8 = ch % 48;
            *(uint4*)(Bs + row * LROW + c8 * 16) =
                *(const uint4*)&xb[((size_t)(t + 1) * BATCH + bbase + row) * 384 + c8 * 8];
        }

        // team barrier: 24 flag lines polled in parallel by wave 0 only
        if (wv == 0 && lane < TEAM_WGS) {
            const unsigned* fp = flags + (team * TEAM_WGS + lane) * 16;
            while (__hip_atomic_load(fp, __ATOMIC_RELAXED,
                                     __HIP_MEMORY_SCOPE_AGENT) < (unsigned)(t + 1)) {
            }
        }
        __syncthreads();

        // bulk h load: 16 rows x 192 u64 = 3072 (12 per thread), ONCE
        {
            const unsigned long long* src64 =
                (const unsigned long long*)xh32 + (size_t)(t & 1) * BATCH * 192;
            unsigned long long v[12];
            #pragma unroll
            for (int i = 0; i < 12; ++i) {
                int g = tid + i * 256;             // 0..3071
                int row = g / 192, du = g % 192;
                v[i] = __hip_atomic_load(&src64[(size_t)(bbase + row) * 192 + du],
                                         __ATOMIC_RELAXED, __HIP_MEMORY_SCOPE_AGENT);
            }
            #pragma unroll
            for (int i = 0; i < 12; ++i) {
                int g = tid + i * 256;
                int row = g / 192, du = g % 192;
                *(unsigned long long*)(Bs + row * LROW + XOFF + du * 8) = v[i];
            }
        }
        __syncthreads();   // (b) new h visible to all waves
    }
}

// ---------------------------------------------------------------------------
extern "C" void kernel_launch(void* const* d_in, const int* in_sizes, int n_in,
                              void* d_out, int out_size, void* d_ws, size_t ws_size,
                              hipStream_t stream) {
    (void)in_sizes; (void)n_in; (void)out_size; (void)ws_size;
    const float* x    = (const float*)d_in[0];
    const float* h0   = (const float*)d_in[1];
    const float* c0   = (const float*)d_in[2];
    const float* W    = (const float*)d_in[3];
    const float* U    = (const float*)d_in[4];
    const float* bias = (const float*)d_in[5];
    const float* G    = (const float*)d_in[6];
    float* out = (float*)d_out;

    char* wsb = (char*)d_ws;
    unsigned* bar = (unsigned*)wsb;                                    // 16 KB
    __bf16* VmT  = (__bf16*)(wsb + 16384);                             // 6.75 MB
    __bf16* xb   = (__bf16*)(wsb + 16384 + (size_t)GATES * KV * 2);    // 12.6 MB
    unsigned* xh32 = (unsigned*)(wsb + 16384 + (size_t)GATES * KV * 2
                                      + (size_t)SEQ * BATCH * 384 * 2);   // 393 KB

    hipMemsetAsync(bar, 0, 16384, stream);
    prep_kernel<<<dim3(18, 48), 256, 0, stream>>>(W, U, G, VmT);
    prep_x<<<dim3(3072), 256, 0, stream>>>(x, xb);
    scan_kernel<<<dim3(NWG), dim3(256), 0, stream>>>(xb, h0, c0, VmT, bias,
                                                     out, xh32, bar);
}

// Round 7
// 573.262 us; speedup vs baseline: 1.3000x; 1.0122x over previous
//
#include <hip/hip_runtime.h>
#include <hip/hip_bf16.h>

// GraphLSTM: B=128, S=128, N=24, F=16, H=32 -> IS=384, HS=768, gates=3072.
// R14 = R13 (580us total: flag barrier, wave0 poll, conflict-free pitch)
// + phase-split MFMA overlapping the flag RTT -- R12's idea with its two
// isolated regressors removed (4-wave poll, per-step global x loads):
//  * LDS row = [x0:768B | x1:768B | h:1536B], pitch 3120B (3120/16=195,
//    195%8==3 -> R13-validated even window spread, linear addressing).
//  * phase A (x-part, kk 0..11) for step t+1 computed BETWEEN flag publish
//    and wave0 poll, reading the double-buffered x from LDS.
//  * out stores moved after flag publish: sync(a) drains only the 1-dword
//    exchange store; out-write latency lands in the poll window.
//  * x_{t+2} staged into the idle x buffer in the same window.
// Accumulation order still kk 0..35 ascending -> same absmax.

typedef __bf16 bf16x8 __attribute__((ext_vector_type(8)));
typedef float f32x4 __attribute__((ext_vector_type(4)));

#define HS 768
#define GATES 3072
#define KV 1152          // combined K: 384 (W) + 768 (U)
#define SEQ 128
#define BATCH 128
#define OUT_HID (BATCH*SEQ*HS)
#define LROW 3120        // LDS row pitch (bytes); /16 % 8 == 3 -> even spread
#define HOFF 1536        // h region offset within a row
#define NWG 192
#define TEAM_WGS 24

__device__ __forceinline__ float fast_sig(float x) {
    return 1.0f / (1.0f + __expf(-x));
}
__device__ __forceinline__ float fast_tanh(float x) {
    x = fminf(fmaxf(x, -15.0f), 15.0f);
    float e = __expf(2.0f * x);
    return (e - 1.0f) / (e + 1.0f);
}

// convert 8 consecutive fp32 -> bf16x8 (RNE via cast)
__device__ __forceinline__ bf16x8 cvt8(const float* src) {
    float4 v0 = *(const float4*)src;
    float4 v1 = *(const float4*)(src + 4);
    bf16x8 p;
    p[0] = (__bf16)v0.x; p[1] = (__bf16)v0.y; p[2] = (__bf16)v0.z; p[3] = (__bf16)v0.w;
    p[4] = (__bf16)v1.x; p[5] = (__bf16)v1.y; p[6] = (__bf16)v1.z; p[7] = (__bf16)v1.w;
    return p;
}

// ---------------------------------------------------------------------------
// Kernel 1: masked + transposed weights (fp32 in, bf16 out).   [R4-validated]
// ---------------------------------------------------------------------------
__global__ void prep_kernel(const float* __restrict__ W, const float* __restrict__ U,
                            const float* __restrict__ G, __bf16* __restrict__ VmT) {
    __shared__ __bf16 tile[64][65];
    const int kvb = blockIdx.x * 64;
    const int cb  = blockIdx.y * 64;
    const int tid = threadIdx.x;
    {
        const int cl = tid & 63, kl0 = tid >> 6;
        #pragma unroll
        for (int i = 0; i < 16; ++i) {
            int kl = kl0 + i * 4;
            int kv = kvb + kl;
            int c  = cb + cl;
            int nout = (c % HS) >> 5;
            float g, v;
            if (kv < 384) {
                g = G[(kv >> 4) * 24 + nout];
                v = W[(size_t)kv * GATES + c];
            } else {
                int ku = kv - 384;
                g = G[(ku >> 5) * 24 + nout];
                v = U[(size_t)ku * GATES + c];
            }
            tile[kl][cl] = (__bf16)(v * g);
        }
    }
    __syncthreads();
    {
        const int kl = tid & 63, cl0 = tid >> 6;
        #pragma unroll
        for (int i = 0; i < 16; ++i) {
            int c = cl0 + i * 4;
            VmT[(size_t)(cb + c) * KV + kvb + kl] = tile[kl][c];
        }
    }
}

// ---------------------------------------------------------------------------
// Kernel 2: x fp32 [b][t][384] -> bf16 [t][b][384]
// ---------------------------------------------------------------------------
__global__ void prep_x(const float* __restrict__ x, __bf16* __restrict__ xb) {
    const int g = blockIdx.x * 256 + threadIdx.x;
    const int e = g * 8;
    const int b = e / (SEQ * 384);
    const int rem = e - b * (SEQ * 384);
    const int t = rem / 384;
    const int k = rem - t * 384;
    *(bf16x8*)&xb[((size_t)t * BATCH + b) * 384 + k] = cvt8(&x[e]);
}

// ---------------------------------------------------------------------------
// Kernel 3: persistent scan. 8 teams x 24 WGs = 192 WGs, 1 WG/CU.
// bar layout (16 KB, zeroed per launch):
//   flags: u32[8][24][16] -- one 64B line per (team,wg), value = t+1
// Per step: phase B MFMA (h-part, 24 ds_read) -> LSTM -> exchange store ->
// sync(a, drains 1 store) -> tid0 flag -> out stores -> phase A MFMA for
// t+1 (x-part from LDS dbuf) -> stage x_{t+2} -> wave0 poll -> sync ->
// bulk h load (12 u64/thread) -> LDS write -> sync(b).
// ---------------------------------------------------------------------------
__global__ __launch_bounds__(256, 1) void scan_kernel(
        const __bf16* __restrict__ xb,     // [t][b][384] bf16
        const float* __restrict__ h0,
        const float* __restrict__ c0,
        const __bf16* __restrict__ VmT,    // [3072][1152] bf16
        const float* __restrict__ bias,
        float* out,
        unsigned* xh32,                    // [2][128][384] packed bf16 pairs
        unsigned* bar) {
    __shared__ __align__(16) char Bs[16 * LROW];   // 49920 B
    const int tid = threadIdx.x;
    const int lane = tid & 63, wv = tid >> 6;
    const int m = lane & 15, quad = lane >> 4;
    const int team = blockIdx.x & 7, wg = blockIdx.x >> 3;
    const int bbase = team * 16;
    const int jbase = wg * 32 + wv * 8;

    unsigned* flags = bar;                              // [8][24][16]
    unsigned* myflag = flags + (team * TEAM_WGS + wg) * 16;

    // --- weights -> registers (read VmT exactly once for the whole scan) ---
    bf16x8 w[2][36];
    #pragma unroll
    for (int T = 0; T < 2; ++T) {
        const int cg = (m & 3) * HS + jbase + 2 * (m >> 2) + T;
        const __bf16* wp = VmT + (size_t)cg * KV;
        #pragma unroll
        for (int kk = 0; kk < 36; ++kk)
            w[T][kk] = *(const bf16x8*)(wp + kk * 32 + quad * 8);
    }

    const int b_own = bbase + m;
    const int j0 = jbase + 2 * quad;       // even
    const int j1 = j0 + 1;                 // odd (adjacent -> one u32)
    float cv0 = c0[b_own * HS + j0];
    float cv1 = c0[b_own * HS + j1];
    f32x4 bias0, bias1;
    #pragma unroll
    for (int r = 0; r < 4; ++r) {
        bias0[r] = bias[r * HS + j0];
        bias1[r] = bias[r * HS + j1];
    }

    // --- pre-loop staging: x_0 -> buf0, x_1 -> buf1, h0 -> h region ---
    #pragma unroll
    for (int i = 0; i < 3; ++i) {
        int ch = tid + i * 256;            // 768 x-chunks (16B)
        int row = ch / 48, c8 = ch % 48;
        *(uint4*)(Bs + row * LROW + c8 * 16) =
            *(const uint4*)&xb[((size_t)0 * BATCH + bbase + row) * 384 + c8 * 8];
        *(uint4*)(Bs + row * LROW + 768 + c8 * 16) =
            *(const uint4*)&xb[((size_t)1 * BATCH + bbase + row) * 384 + c8 * 8];
    }
    #pragma unroll
    for (int i = 0; i < 6; ++i) {
        int ch = tid + i * 256;            // 1536 h-chunks (bf16x8)
        int row = ch / 96, c8h = ch % 96;
        bf16x8 p = cvt8(&h0[(size_t)(bbase + row) * HS + c8h * 8]);
        *(bf16x8*)(Bs + row * LROW + HOFF + c8h * 16) = p;
    }
    __syncthreads();

    // --- phase A for step 0: bias + x-part (kk 0..11) from buf0 ---
    f32x4 accA0 = bias0, accA1 = bias1;
    {
        const char* xf = Bs + m * LROW + quad * 16;
        #pragma unroll
        for (int kk = 0; kk < 12; ++kk) {
            bf16x8 bf = *(const bf16x8*)(xf + kk * 64);
            accA0 = __builtin_amdgcn_mfma_f32_16x16x32_bf16(w[0][kk], bf, accA0, 0, 0, 0);
            accA1 = __builtin_amdgcn_mfma_f32_16x16x32_bf16(w[1][kk], bf, accA1, 0, 0, 0);
        }
    }

    #pragma unroll 1
    for (int t = 0; t < SEQ; ++t) {
        // phase B: h-part (kk 12..35) from LDS h region
        f32x4 acc0 = accA0, acc1 = accA1;
        const char* hf = Bs + m * LROW + HOFF + quad * 16;
        #pragma unroll
        for (int p = 0; p < 24; ++p) {
            bf16x8 bf = *(const bf16x8*)(hf + p * 64);
            acc0 = __builtin_amdgcn_mfma_f32_16x16x32_bf16(w[0][12 + p], bf, acc0, 0, 0, 0);
            acc1 = __builtin_amdgcn_mfma_f32_16x16x32_bf16(w[1][12 + p], bf, acc1, 0, 0, 0);
        }

        // LSTM elementwise (lane-local: acc reg index == gate i,f,g,o)
        float h0v, h1v;
        {
            float ii = fast_sig(acc0[0]), ff = fast_sig(acc0[1]);
            float gg = fast_tanh(acc0[2]), oo = fast_sig(acc0[3]);
            cv0 = ff * cv0 + ii * gg;
            h0v = oo * fast_tanh(cv0);
        }
        {
            float ii = fast_sig(acc1[0]), ff = fast_sig(acc1[1]);
            float gg = fast_tanh(acc1[2]), oo = fast_sig(acc1[3]);
            cv1 = ff * cv1 + ii * gg;
            h1v = oo * fast_tanh(cv1);
        }

        if (t == SEQ - 1) {
            const size_t obase = ((size_t)b_own * SEQ + t) * HS;
            *(float2*)&out[obase + j0] = make_float2(h0v, h1v);
            *(float2*)&out[OUT_HID + b_own * HS + j0] = make_float2(h0v, h1v);
            *(float2*)&out[OUT_HID + BATCH * HS + b_own * HS + j0] = make_float2(cv0, cv1);
            break;
        }

        // exchange store (only vmem op outstanding at sync(a))
        {
            unsigned lo = (unsigned)__builtin_bit_cast(unsigned short, (__bf16)h0v);
            unsigned hi = (unsigned)__builtin_bit_cast(unsigned short, (__bf16)h1v);
            unsigned* dst = xh32 + ((size_t)(t & 1) * BATCH + b_own) * 384
                                 + (jbase >> 1) + quad;
            __hip_atomic_store(dst, lo | (hi << 16), __ATOMIC_RELAXED,
                               __HIP_MEMORY_SCOPE_AGENT);
        }

        __syncthreads();   // (a) LDS reads done + all waves' exchange stores drained

        // publish: one relaxed flag store per WG (own 64B line, no RMW)
        if (tid == 0)
            __hip_atomic_store(myflag, (unsigned)(t + 1), __ATOMIC_RELAXED,
                               __HIP_MEMORY_SCOPE_AGENT);

        // out stores: latency lands in the poll window
        {
            const size_t obase = ((size_t)b_own * SEQ + t) * HS;
            *(float2*)&out[obase + j0] = make_float2(h0v, h1v);
        }

        // phase A for step t+1: bias + x-part from the other LDS x buffer
        accA0 = bias0; accA1 = bias1;
        {
            const char* xf = Bs + m * LROW + (((t + 1) & 1) ? 768 : 0) + quad * 16;
            #pragma unroll
            for (int kk = 0; kk < 12; ++kk) {
                bf16x8 bf = *(const bf16x8*)(xf + kk * 64);
                accA0 = __builtin_amdgcn_mfma_f32_16x16x32_bf16(w[0][kk], bf, accA0, 0, 0, 0);
                accA1 = __builtin_amdgcn_mfma_f32_16x16x32_bf16(w[1][kk], bf, accA1, 0, 0, 0);
            }
        }

        // stage x_{t+2} into the x buffer just freed by phase A's producer
        if (t + 2 < SEQ) {
            const int xoff = (t & 1) ? 768 : 0;    // (t+2)&1 == t&1
            #pragma unroll
            for (int i = 0; i < 3; ++i) {
                int ch = tid + i * 256;
                int row = ch / 48, c8 = ch % 48;
                *(uint4*)(Bs + row * LROW + xoff + c8 * 16) =
                    *(const uint4*)&xb[((size_t)(t + 2) * BATCH + bbase + row) * 384 + c8 * 8];
            }
        }

        // team barrier: 24 flag lines polled in parallel by wave 0 only
        if (wv == 0 && lane < TEAM_WGS) {
            const unsigned* fp = flags + (team * TEAM_WGS + lane) * 16;
            while (__hip_atomic_load(fp, __ATOMIC_RELAXED,
                                     __HIP_MEMORY_SCOPE_AGENT) < (unsigned)(t + 1)) {
            }
        }
        __syncthreads();

        // bulk h load: 16 rows x 192 u64 = 3072 (12 per thread), ONCE
        {
            const unsigned long long* src64 =
                (const unsigned long long*)xh32 + (size_t)(t & 1) * BATCH * 192;
            unsigned long long v[12];
            #pragma unroll
            for (int i = 0; i < 12; ++i) {
                int g = tid + i * 256;             // 0..3071
                int row = g / 192, du = g % 192;
                v[i] = __hip_atomic_load(&src64[(size_t)(bbase + row) * 192 + du],
                                         __ATOMIC_RELAXED, __HIP_MEMORY_SCOPE_AGENT);
            }
            #pragma unroll
            for (int i = 0; i < 12; ++i) {
                int g = tid + i * 256;
                int row = g / 192, du = g % 192;
                *(unsigned long long*)(Bs + row * LROW + HOFF + du * 8) = v[i];
            }
        }
        __syncthreads();   // (b) new h visible to all waves
    }
}

// ---------------------------------------------------------------------------
extern "C" void kernel_launch(void* const* d_in, const int* in_sizes, int n_in,
                              void* d_out, int out_size, void* d_ws, size_t ws_size,
                              hipStream_t stream) {
    (void)in_sizes; (void)n_in; (void)out_size; (void)ws_size;
    const float* x    = (const float*)d_in[0];
    const float* h0   = (const float*)d_in[1];
    const float* c0   = (const float*)d_in[2];
    const float* W    = (const float*)d_in[3];
    const float* U    = (const float*)d_in[4];
    const float* bias = (const float*)d_in[5];
    const float* G    = (const float*)d_in[6];
    float* out = (float*)d_out;

    char* wsb = (char*)d_ws;
    unsigned* bar = (unsigned*)wsb;                                    // 16 KB
    __bf16* VmT  = (__bf16*)(wsb + 16384);                             // 6.75 MB
    __bf16* xb   = (__bf16*)(wsb + 16384 + (size_t)GATES * KV * 2);    // 12.6 MB
    unsigned* xh32 = (unsigned*)(wsb + 16384 + (size_t)GATES * KV * 2
                                      + (size_t)SEQ * BATCH * 384 * 2);   // 393 KB

    hipMemsetAsync(bar, 0, 16384, stream);
    prep_kernel<<<dim3(18, 48), 256, 0, stream>>>(W, U, G, VmT);
    prep_x<<<dim3(3072), 256, 0, stream>>>(x, xb);
    scan_kernel<<<dim3(NWG), dim3(256), 0, stream>>>(xb, h0, c0, VmT, bias,
                                                     out, xh32, bar);
}